// Round 10
// baseline (1095.325 us; speedup 1.0000x reference)
//
#include <hip/hip_runtime.h>

#define N_PTS 4096
#define NB    8
#define KNN   20
#define FIN   67
#define COUT  64

typedef unsigned short u16;
typedef unsigned int   u32;
typedef unsigned long long u64;

__device__ __forceinline__ u32 umin32(u32 a, u32 b) { return a < b ? a : b; }

// Order-preserving f32 -> u32 map (no NaNs in finite-distance data).
__device__ __forceinline__ u32 fmap(float f) {
    u32 b = __float_as_uint(f);
    return b ^ ((u32)((int)b >> 31) | 0x80000000u);
}

template <int CTRL>
__device__ __forceinline__ u32 dpp_mov(u32 v) {
    return (u32)__builtin_amdgcn_update_dpp((int)v, (int)v, CTRL, 0xF, 0xF, false);
}

// Min across all 64 lanes, returned uniform (proven correct in round 8).
__device__ __forceinline__ u32 wave_min_u32(u32 v) {
    v = umin32(v, dpp_mov<0x121>(v));   // row_ror:1
    v = umin32(v, dpp_mov<0x122>(v));   // row_ror:2
    v = umin32(v, dpp_mov<0x124>(v));   // row_ror:4
    v = umin32(v, dpp_mov<0x128>(v));   // row_ror:8  -> row16 min in every lane
    u32 a = (u32)__builtin_amdgcn_readlane((int)v, 0);
    u32 b = (u32)__builtin_amdgcn_readlane((int)v, 16);
    u32 c = (u32)__builtin_amdgcn_readlane((int)v, 32);
    u32 d = (u32)__builtin_amdgcn_readlane((int)v, 48);
    return umin32(umin32(a, b), umin32(c, d));
}

// sq = (x*x + y*y) + z*z, all f32, no FMA (matches np op order).
__device__ __forceinline__ float sq_exact(float x, float y, float z) {
#pragma clang fp contract(off)
    float s = (x * x + y * y) + z * z;
    return s;
}

// dist = (sq_i - 2*dot) + sq_j, dot = (x_i*x_j + y_i*y_j) + z_i*z_j, no FMA.
// sqj precomputed from the same inputs with sq_exact -> value bit-identical.
__device__ __forceinline__ float dist_from_sq(float xi, float yi, float zi, float sqi,
                                              float xj, float yj, float zj, float sqj) {
#pragma clang fp contract(off)
    float d0 = xi * xj, d1 = yi * yj, d2 = zi * zj;
    float dot = (d0 + d1) + d2;
    float d = (sqi - 2.0f * dot) + sqj;
    return d;
}

__device__ __forceinline__ float dist_exact(float xi, float yi, float zi, float sqi,
                                            float xj, float yj, float zj) {
#pragma clang fp contract(off)
    float d0 = xi * xj, d1 = yi * yj, d2 = zi * zj;
    float dot = (d0 + d1) + d2;
    float sqj = (xj * xj + yj * yj) + zj * zj;
    float d = (sqi - 2.0f * dot) + sqj;
    return d;
}

__device__ __forceinline__ void insert3(float d, int c,
                                        float& v0, float& v1, float& v2,
                                        int& c0, int& c1, int& c2) {
    if (d < v2) {
        if (d < v1) {
            if (d < v0) { v2 = v1; c2 = c1; v1 = v0; c1 = c0; v0 = d; c0 = c; }
            else        { v2 = v1; c2 = c1; v1 = d;  c1 = c; }
        } else          { v2 = d;  c2 = c; }
    }
}

// ---------------- Kernel 1: kNN, LDS-staged candidates ----------------
// Block = 256 threads = 4 waves = 4 queries. The 4096 candidates (x,y,z,sq
// packed float4, 64 KB LDS) are staged ONCE per block and shared by the 4
// waves -> no per-wave 48 KB L1/MSHR stream (the round-8 bottleneck).
// Per wave: lane's candidate q is j = q*64+lane (lane-stride-16B b128 reads,
// conflict-free). Selection = per-lane top-3 + 20 DPP extraction rounds
// (round-8-proven), all scalars -> no spill (the round-9 bug).
__global__ __launch_bounds__(256) void knn_lds_kernel(
    const float* __restrict__ xloc, u16* __restrict__ knn_out) {
    __shared__ float4 pack[N_PTS];            // 64 KB
    const int tid   = threadIdx.x;
    const int lane  = tid & 63;
    const int wid   = tid >> 6;
    const int blk   = blockIdx.x;             // b*1024 + qtile
    const int b     = blk >> 10;
    const int i     = ((blk & 1023) << 2) | wid;   // this wave's query (in batch)
    const float* xb = xloc + (size_t)b * 3 * N_PTS;

    for (int w = 0; w < 16; ++w) {
        int c = w * 256 + tid;
        float x = xb[c], y = xb[N_PTS + c], z = xb[2 * N_PTS + c];
        pack[c] = make_float4(x, y, z, sq_exact(x, y, z));
    }
    __syncthreads();

    const float4 qp  = pack[i];
    const float xi = qp.x, yi = qp.y, zi = qp.z, sqi = qp.w;

    // Per-lane sorted top-3 over its 64 candidates (slot q -> j = q*64+lane).
    float v0 = 1e30f, v1 = 1e30f, v2 = 1e30f;
    int   c0 = -1,    c1 = -1,    c2 = -1;

#pragma unroll 4
    for (int q = 0; q < 64; ++q) {
        int j = (q << 6) | lane;
        float4 p = pack[j];
        float d = (j == i) ? 1e30f : dist_from_sq(xi, yi, zi, sqi, p.x, p.y, p.z, p.w);
        insert3(d, q, v0, v1, v2, c0, c1, c2);
    }

    u64 taken = 0;
    int myknn = 0;

    for (int t = 0; t < KNN; ++t) {
        // (dist, idx) lexicographic argmin across the wave, DPP+scalar (r8-proven).
        u32 key  = fmap(v0);
        int j0   = (c0 >= 0) ? ((c0 << 6) | lane) : 0x3FFFFFFF;
        u32 smin = wave_min_u32(key);
        u32 myj  = (key == smin) ? (u32)j0 : 0x7FFFFFFFu;
        u32 jmin = wave_min_u32(myj);

        if (lane == t) myknn = (int)jmin;

        bool owner = (key == smin) && ((u32)j0 == jmin);
        if (owner) {
            taken |= (1ull << c0);            // c0 == j0>>6 == slot q
            v0 = v1; c0 = c1; v1 = v2; c1 = c2; v2 = 1e30f; c2 = -1;
            if (v0 >= 1e30f) {
                // Rare: rebuild top-3 from remaining candidates (identical rounding).
                v0 = v1 = v2 = 1e30f; c0 = c1 = c2 = -1;
                for (int q = 0; q < 64; ++q) {
                    if ((taken >> q) & 1ull) continue;
                    int j = (q << 6) | lane;
                    if (j == i) continue;
                    float4 p = pack[j];
                    float d = dist_from_sq(xi, yi, zi, sqi, p.x, p.y, p.z, p.w);
                    insert3(d, q, v0, v1, v2, c0, c1, c2);
                }
            }
        }
    }

    const int row = (b << 12) | i;
    if (lane < KNN) knn_out[(size_t)row * KNN + lane] = (u16)myknn;
}

// ---------------- Kernel 2: conv, coalesced tile ----------------
// Block = 128 threads = 128 consecutive points (lane = point). Feature rows
// are double-buffer staged into LDS (coalesced); each thread does 20 LDS
// gathers per row and accumulates the GEMV on the fly into static registers.
// ALL global writes are lane-consecutive -> no write amplification (the
// round-7 1.4 GB WRITE_SIZE bug).
__global__ __launch_bounds__(128) void conv_tile_kernel(
    const float* __restrict__ xloc,
    const float* __restrict__ xfeat,
    const float* __restrict__ Wrel,
    const float* __restrict__ brel,
    const float* __restrict__ Wroot,
    const u16* __restrict__ knn_in,
    float* __restrict__ out) {
    __shared__ float rowbuf[2][N_PTS];        // 32 KB
    const int tid = threadIdx.x;
    const int blk = blockIdx.x;               // b*32 + tile
    const int b   = blk >> 5;
    const int i   = ((blk & 31) << 7) | tid;  // point index within batch
    const float* xb = xloc + (size_t)b * 3 * N_PTS;
    const float* fb = xfeat + (size_t)b * 64 * N_PTS;

    // Output 0 passthrough (bit-exact, coalesced).
#pragma unroll
    for (int c = 0; c < 3; ++c)
        out[((size_t)b * 3 + c) * N_PTS + i] = xb[(size_t)c * N_PTS + i];

    // This thread's neighbor list -> registers (static indexing only).
    u32 kl[KNN / 2];
    const u32* kp = (const u32*)(knn_in + (size_t)((b << 12) | i) * KNN);
#pragma unroll
    for (int w = 0; w < KNN / 2; ++w) kl[w] = kp[w];
    int jj[KNN];
#pragma unroll
    for (int t = 0; t < KNN; ++t) jj[t] = (int)((kl[t >> 1] >> ((t & 1) * 16)) & 0xFFFFu);

    float rel[COUT], root[COUT];
#pragma unroll
    for (int c = 0; c < COUT; ++c) { rel[c] = 0.f; root[c] = 0.f; }

    // Stage feature row f into rowbuf[f&1] (coalesced, 8 float4 per thread).
    auto stage = [&](int f) {
        const float* src = (f < 3) ? (xb + (size_t)f * N_PTS)
                                   : (fb + (size_t)(f - 3) * N_PTS);
        const float4* s4 = (const float4*)src;
        float4* d4 = (float4*)rowbuf[f & 1];
#pragma unroll
        for (int w = 0; w < 8; ++w) {
            int idx = w * 128 + tid;
            d4[idx] = s4[idx];
        }
    };

    stage(0);
    __syncthreads();

    for (int f = 0; f < FIN; ++f) {
        if (f + 1 < FIN) stage(f + 1);        // fills buf[(f+1)&1] while we read buf[f&1]
        const float* cur = rowbuf[f & 1];
        float hf = cur[i];
        float af = 0.f;
#pragma unroll
        for (int t = 0; t < KNN; ++t) af += cur[jj[t]];   // ascending (dist,idx) order

        const float4* w4r = (const float4*)(Wrel + f * COUT);
        const float4* w4o = (const float4*)(Wroot + f * COUT);
#pragma unroll
        for (int c4 = 0; c4 < COUT / 4; ++c4) {
            float4 wr = w4r[c4], wo = w4o[c4];
            rel[c4 * 4 + 0] += af * wr.x;  root[c4 * 4 + 0] += hf * wo.x;
            rel[c4 * 4 + 1] += af * wr.y;  root[c4 * 4 + 1] += hf * wo.y;
            rel[c4 * 4 + 2] += af * wr.z;  root[c4 * 4 + 2] += hf * wo.z;
            rel[c4 * 4 + 3] += af * wr.w;  root[c4 * 4 + 3] += hf * wo.w;
        }
        __syncthreads();
    }

    const size_t ob = (size_t)NB * 3 * N_PTS + (size_t)b * COUT * N_PTS;
#pragma unroll
    for (int c = 0; c < COUT; ++c) {
        float acc = (rel[c] + brel[c]) + root[c];   // einsum + b_rel + einsum order
        out[ob + (size_t)c * N_PTS + i] = fmaxf(acc, 0.f);
    }
}

// ---------------- Fallback: proven round-6/7 monolithic kernel ----------------
__global__ __launch_bounds__(64) void pcd_all(
    const float* __restrict__ xloc,
    const float* __restrict__ xfeat,
    const float* __restrict__ Wrel,
    const float* __restrict__ brel,
    const float* __restrict__ Wroot,
    float* __restrict__ out) {
    const int lane = threadIdx.x;
    const int row  = blockIdx.x;
    const int b    = row >> 12;
    const int i    = row & (N_PTS - 1);
    const float* xb = xloc + (size_t)b * 3 * N_PTS;

    if (lane < 3) {
        out[((size_t)b * 3 + lane) * N_PTS + i] = xb[(size_t)lane * N_PTS + i];
    }

    const float xi  = xb[i];
    const float yi  = xb[N_PTS + i];
    const float zi  = xb[2 * N_PTS + i];
    const float sqi = sq_exact(xi, yi, zi);

    float v0 = 1e30f, v1 = 1e30f, v2 = 1e30f;
    int   c0 = -1,    c1 = -1,    c2 = -1;

    for (int s = 0; s < 16; ++s) {
        int jb = s * 256 + lane * 4;
        float4 fx = *(const float4*)(xb + jb);
        float4 fy = *(const float4*)(xb + N_PTS + jb);
        float4 fz = *(const float4*)(xb + 2 * N_PTS + jb);
#pragma unroll
        for (int q = 0; q < 4; ++q) {
            float xj = (q == 0) ? fx.x : (q == 1) ? fx.y : (q == 2) ? fx.z : fx.w;
            float yj = (q == 0) ? fy.x : (q == 1) ? fy.y : (q == 2) ? fy.z : fy.w;
            float zj = (q == 0) ? fz.x : (q == 1) ? fz.y : (q == 2) ? fz.z : fz.w;
            int j = jb + q;
            float d = (j == i) ? 1e30f : dist_exact(xi, yi, zi, sqi, xj, yj, zj);
            insert3(d, s * 4 + q, v0, v1, v2, c0, c1, c2);
        }
    }

    u64 taken = 0;
    __shared__ int knn[KNN];

    for (int t = 0; t < KNN; ++t) {
        float bv = v0;
        int   bj = (c0 >= 0) ? (((c0 >> 2) << 8) + lane * 4 + (c0 & 3)) : (N_PTS - 1);
#pragma unroll
        for (int m = 1; m < 64; m <<= 1) {
            float ov = __shfl_xor(bv, m);
            int   oj = __shfl_xor(bj, m);
            if (ov < bv || (ov == bv && oj < bj)) { bv = ov; bj = oj; }
        }
        if (lane == 0) knn[t] = bj & (N_PTS - 1);
        int owner = (bj >> 2) & 63;
        if (lane == owner) {
            int cw = (((bj >> 8) << 2) | (bj & 3)) & 63;
            taken |= (1ull << cw);
            v0 = v1; c0 = c1; v1 = v2; c1 = c2; v2 = 1e30f; c2 = -1;
            if (v0 >= 1e30f) {
                v0 = v1 = v2 = 1e30f; c0 = c1 = c2 = -1;
                for (int s = 0; s < 16; ++s) {
                    int jb = s * 256 + lane * 4;
                    float4 fx = *(const float4*)(xb + jb);
                    float4 fy = *(const float4*)(xb + N_PTS + jb);
                    float4 fz = *(const float4*)(xb + 2 * N_PTS + jb);
#pragma unroll
                    for (int q = 0; q < 4; ++q) {
                        int cc = s * 4 + q;
                        if ((taken >> cc) & 1ull) continue;
                        int j = jb + q;
                        if (j == i) continue;
                        float xj = (q == 0) ? fx.x : (q == 1) ? fx.y : (q == 2) ? fx.z : fx.w;
                        float yj = (q == 0) ? fy.x : (q == 1) ? fy.y : (q == 2) ? fy.z : fy.w;
                        float zj = (q == 0) ? fz.x : (q == 1) ? fz.y : (q == 2) ? fz.z : fz.w;
                        float d = dist_exact(xi, yi, zi, sqi, xj, yj, zj);
                        insert3(d, cc, v0, v1, v2, c0, c1, c2);
                    }
                }
            }
        }
    }

    __syncthreads();

    __shared__ float aggf[FIN + 1];
    __shared__ float hif[FIN + 1];

    const float* xfb = xfeat + ((size_t)b * 64 + lane) * N_PTS;
    const float* xlb = xb + (size_t)(lane < 3 ? lane : 0) * N_PTS;
    float af = 0.f, al = 0.f;
    for (int t = 0; t < KNN; ++t) {
        int j = knn[t];
        af += xfb[j];
        if (lane < 3) al += xlb[j];
    }
    aggf[3 + lane] = af;
    hif[3 + lane]  = xfb[i];
    if (lane < 3) { aggf[lane] = al; hif[lane] = xlb[i]; }
    __syncthreads();

    float acc_rel = 0.f, acc_root = 0.f;
    for (int f = 0; f < FIN; ++f) {
        acc_rel  += aggf[f] * Wrel[f * COUT + lane];
        acc_root += hif[f]  * Wroot[f * COUT + lane];
    }
    float acc = (acc_rel + brel[lane]) + acc_root;
    acc = fmaxf(acc, 0.0f);
    out[(size_t)NB * 3 * N_PTS + ((((size_t)b << 6) | lane) << 12) + i] = acc;
}

extern "C" void kernel_launch(void* const* d_in, const int* in_sizes, int n_in,
                              void* d_out, int out_size, void* d_ws, size_t ws_size,
                              hipStream_t stream) {
    const float* xloc  = nullptr;
    const float* xfeat = nullptr;
    const float* Wrel  = nullptr;
    const float* brel  = nullptr;
    const float* Wroot = nullptr;
    for (int idx = 0; idx < n_in; ++idx) {
        const long long s = in_sizes[idx];
        const float* p = (const float*)d_in[idx];
        if (s == 98304LL || s == 393216LL)          { xloc = p; }
        else if (s == 2097152LL || s == 8388608LL)  { xfeat = p; }
        else if (s == 4288LL || s == 17152LL)       { if (!Wrel) Wrel = p; else Wroot = p; }
        else if (s == 64LL || s == 256LL)           { brel = p; }
    }
    if (!xloc || !xfeat || !Wrel || !brel || !Wroot) {
        xloc  = (const float*)d_in[0];
        xfeat = (const float*)d_in[1];
        Wrel  = (const float*)d_in[2];
        brel  = (const float*)d_in[3];
        Wroot = (const float*)d_in[4];
    }

    const size_t KNN_BYTES = (size_t)NB * N_PTS * KNN * sizeof(u16);  // 1.31 MB
    if (d_ws != nullptr && ws_size >= KNN_BYTES) {
        u16* knn_ws = (u16*)d_ws;
        knn_lds_kernel<<<dim3(NB * N_PTS / 4), dim3(256), 0, stream>>>(xloc, knn_ws);
        conv_tile_kernel<<<dim3(NB * 32), dim3(128), 0, stream>>>(
            xloc, xfeat, Wrel, brel, Wroot, knn_ws, (float*)d_out);
    } else {
        pcd_all<<<dim3(NB * N_PTS), dim3(64), 0, stream>>>(
            xloc, xfeat, Wrel, brel, Wroot, (float*)d_out);
    }
}

// Round 11
// 906.401 us; speedup vs baseline: 1.2084x; 1.2084x over previous
//
#include <hip/hip_runtime.h>

#define N_PTS 4096
#define NB    8
#define KNN   20
#define FIN   67
#define COUT  64
#define LSZ   24   // exact top-24 list per thread (>= KNN; 24+8=32 for bitonic merge)
#define BSZ   8    // insert shift-buffer

typedef unsigned short u16;
typedef unsigned int   u32;
typedef unsigned long long u64;

__device__ __forceinline__ float finf() { return __uint_as_float(0x7f800000u); }

// sq = (x*x + y*y) + z*z, all f32, no FMA (matches np op order).
__device__ __forceinline__ float sq_exact(float x, float y, float z) {
#pragma clang fp contract(off)
    float s = (x * x + y * y) + z * z;
    return s;
}

// dist = (sq_i - 2*dot) + sq_j, dot = (x_i*x_j + y_i*y_j) + z_i*z_j, no FMA.
__device__ __forceinline__ float dist_from_sq(float xi, float yi, float zi, float sqi,
                                              float xj, float yj, float zj, float sqj) {
#pragma clang fp contract(off)
    float d0 = xi * xj, d1 = yi * yj, d2 = zi * zj;
    float dot = (d0 + d1) + d2;
    float d = (sqi - 2.0f * dot) + sqj;
    return d;
}

__device__ __forceinline__ float dist_exact(float xi, float yi, float zi, float sqi,
                                            float xj, float yj, float zj) {
#pragma clang fp contract(off)
    float d0 = xi * xj, d1 = yi * yj, d2 = zi * zj;
    float dot = (d0 + d1) + d2;
    float sqj = (xj * xj + yj * yj) + zj * zj;
    float d = (sqi - 2.0f * dot) + sqj;
    return d;
}

// Compare-exchange on (d, j) lexicographic (strict) — matches lax.top_k order.
__device__ __forceinline__ void cswap(float& ad, u32& aj, float& bd, u32& bj) {
    bool sw = (bd < ad) || ((bd == ad) && (bj < aj));
    float nad = sw ? bd : ad, nbd = sw ? ad : bd;
    u32   naj = sw ? bj : aj, nbj = sw ? aj : bj;
    ad = nad; bd = nbd; aj = naj; bj = nbj;
}

// sort buffer (Batcher odd-even, 19 comparators) then bitonic-merge into list.
// list stays the exact 24 smallest (d,j) seen so far. All indices static.
__device__ __forceinline__ void sort_merge(float (&ld)[LSZ], u32 (&lj)[LSZ],
                                           float (&bd)[BSZ], u32 (&bj)[BSZ]) {
    cswap(bd[0],bj[0],bd[1],bj[1]); cswap(bd[2],bj[2],bd[3],bj[3]);
    cswap(bd[4],bj[4],bd[5],bj[5]); cswap(bd[6],bj[6],bd[7],bj[7]);
    cswap(bd[0],bj[0],bd[2],bj[2]); cswap(bd[1],bj[1],bd[3],bj[3]);
    cswap(bd[4],bj[4],bd[6],bj[6]); cswap(bd[5],bj[5],bd[7],bj[7]);
    cswap(bd[1],bj[1],bd[2],bj[2]); cswap(bd[5],bj[5],bd[6],bj[6]);
    cswap(bd[0],bj[0],bd[4],bj[4]); cswap(bd[1],bj[1],bd[5],bj[5]);
    cswap(bd[2],bj[2],bd[6],bj[6]); cswap(bd[3],bj[3],bd[7],bj[7]);
    cswap(bd[2],bj[2],bd[4],bj[4]); cswap(bd[3],bj[3],bd[5],bj[5]);
    cswap(bd[1],bj[1],bd[2],bj[2]); cswap(bd[3],bj[3],bd[4],bj[4]);
    cswap(bd[5],bj[5],bd[6],bj[6]);
    // concat: md[0..23] = list (asc), md[24..31] = buffer reversed (desc) -> bitonic
    float md[32]; u32 mj[32];
#pragma unroll
    for (int t = 0; t < LSZ; ++t) { md[t] = ld[t]; mj[t] = lj[t]; }
#pragma unroll
    for (int t = 0; t < BSZ; ++t) { md[LSZ + t] = bd[BSZ - 1 - t]; mj[LSZ + t] = bj[BSZ - 1 - t]; }
#pragma unroll
    for (int k = 16; k >= 1; k >>= 1) {
#pragma unroll
        for (int t = 0; t < 32; ++t) {
            if ((t & k) == 0) cswap(md[t], mj[t], md[t | k], mj[t | k]);
        }
    }
#pragma unroll
    for (int t = 0; t < LSZ; ++t) { ld[t] = md[t]; lj[t] = mj[t]; }
}

// ---------------- Kernel 1: kNN, one query per THREAD ----------------
// 512 blocks x 64 threads; thread = one query. Candidate stream is wave-
// uniform (broadcast loads, software-pipelined). Exact top-24 maintained in
// registers via threshold gate + shift-buffer + static sorting networks.
// No cross-lane ops, no refill path, tiny hot loop.
__global__ __launch_bounds__(64) void knn_pt_kernel(
    const float* __restrict__ xloc, u16* __restrict__ knn_out) {
    const int lane = threadIdx.x;
    const int blk  = blockIdx.x;                 // b*64 + tile
    const int b    = blk >> 6;
    const int i    = ((blk & 63) << 6) | lane;   // this thread's query
    const float* xb = xloc + (size_t)b * 3 * N_PTS;

    const float xi = xb[i], yi = xb[N_PTS + i], zi = xb[2 * N_PTS + i];
    const float sqi = sq_exact(xi, yi, zi);

    float ld[LSZ]; u32 lj[LSZ];
    float bd[BSZ]; u32 bj[BSZ];
#pragma unroll
    for (int t = 0; t < LSZ; ++t) { ld[t] = finf(); lj[t] = 0xFFFFFFFFu; }
#pragma unroll
    for (int t = 0; t < BSZ; ++t) { bd[t] = finf(); bj[t] = 0xFFFFFFFFu; }
    int cnt = 0;
    float thr = finf();

    // Software-pipelined uniform candidate loads (4 candidates per chunk).
    float4 nx = *(const float4*)(xb);
    float4 ny = *(const float4*)(xb + N_PTS);
    float4 nz = *(const float4*)(xb + 2 * N_PTS);

#pragma unroll 1
    for (int c = 0; c < N_PTS; c += 4) {
        float4 cx = nx, cy = ny, cz = nz;
        if (c + 4 < N_PTS) {
            nx = *(const float4*)(xb + c + 4);
            ny = *(const float4*)(xb + N_PTS + c + 4);
            nz = *(const float4*)(xb + 2 * N_PTS + c + 4);
        }
#pragma unroll
        for (int q = 0; q < 4; ++q) {
            float xj = (q == 0) ? cx.x : (q == 1) ? cx.y : (q == 2) ? cx.z : cx.w;
            float yj = (q == 0) ? cy.x : (q == 1) ? cy.y : (q == 2) ? cy.z : cy.w;
            float zj = (q == 0) ? cz.x : (q == 1) ? cz.y : (q == 2) ? cz.z : cz.w;
            float sqj = sq_exact(xj, yj, zj);
            float d = dist_from_sq(xi, yi, zi, sqi, xj, yj, zj, sqj);
            int j = c + q;
            // Gate d < thr is EXACT: a candidate with d == thr has larger j than
            // the list's 24th entry (inserted earlier, ascending-j scan), hence
            // (d,j)-lex rank > 24 forever. Self excluded explicitly.
            bool ok = (j != i) && (d < thr);
            if (ok) {
#pragma unroll
                for (int t = BSZ - 1; t > 0; --t) { bd[t] = bd[t - 1]; bj[t] = bj[t - 1]; }
                bd[0] = d; bj[0] = (u32)j; ++cnt;
            }
        }
        // Merge when any lane's buffer is >= 5 full: next chunk adds at most 4
        // inserts per lane, so a lane can never need a 9th slot. (Entering a
        // chunk cnt<=4; 4th insert lands in slot 7 displacing only stale +inf.)
        if (__any(cnt >= BSZ - 3)) {
            sort_merge(ld, lj, bd, bj);
            thr = ld[LSZ - 1];
#pragma unroll
            for (int t = 0; t < BSZ; ++t) { bd[t] = finf(); bj[t] = 0xFFFFFFFFu; }
            cnt = 0;
        }
    }
    sort_merge(ld, lj, bd, bj);   // drain remaining buffer

    const int row = (b << 12) | i;
#pragma unroll
    for (int t = 0; t < KNN; ++t)
        knn_out[(size_t)row * KNN + t] = (u16)lj[t];
}

// ---------------- Kernel 2: conv, coalesced tile (proven r10, ~160us) ----------------
__global__ __launch_bounds__(128) void conv_tile_kernel(
    const float* __restrict__ xloc,
    const float* __restrict__ xfeat,
    const float* __restrict__ Wrel,
    const float* __restrict__ brel,
    const float* __restrict__ Wroot,
    const u16* __restrict__ knn_in,
    float* __restrict__ out) {
    __shared__ float rowbuf[2][N_PTS];        // 32 KB
    const int tid = threadIdx.x;
    const int blk = blockIdx.x;               // b*32 + tile
    const int b   = blk >> 5;
    const int i   = ((blk & 31) << 7) | tid;  // point index within batch
    const float* xb = xloc + (size_t)b * 3 * N_PTS;
    const float* fb = xfeat + (size_t)b * 64 * N_PTS;

    // Output 0 passthrough (bit-exact, coalesced).
#pragma unroll
    for (int c = 0; c < 3; ++c)
        out[((size_t)b * 3 + c) * N_PTS + i] = xb[(size_t)c * N_PTS + i];

    // This thread's neighbor list -> registers (static indexing only).
    u32 kl[KNN / 2];
    const u32* kp = (const u32*)(knn_in + (size_t)((b << 12) | i) * KNN);
#pragma unroll
    for (int w = 0; w < KNN / 2; ++w) kl[w] = kp[w];
    int jj[KNN];
#pragma unroll
    for (int t = 0; t < KNN; ++t) jj[t] = (int)((kl[t >> 1] >> ((t & 1) * 16)) & 0xFFFFu);

    float rel[COUT], root[COUT];
#pragma unroll
    for (int c = 0; c < COUT; ++c) { rel[c] = 0.f; root[c] = 0.f; }

    auto stage = [&](int f) {
        const float* src = (f < 3) ? (xb + (size_t)f * N_PTS)
                                   : (fb + (size_t)(f - 3) * N_PTS);
        const float4* s4 = (const float4*)src;
        float4* d4 = (float4*)rowbuf[f & 1];
#pragma unroll
        for (int w = 0; w < 8; ++w) {
            int idx = w * 128 + tid;
            d4[idx] = s4[idx];
        }
    };

    stage(0);
    __syncthreads();

    for (int f = 0; f < FIN; ++f) {
        if (f + 1 < FIN) stage(f + 1);
        const float* cur = rowbuf[f & 1];
        float hf = cur[i];
        float af = 0.f;
#pragma unroll
        for (int t = 0; t < KNN; ++t) af += cur[jj[t]];   // ascending (dist,idx) order

        const float4* w4r = (const float4*)(Wrel + f * COUT);
        const float4* w4o = (const float4*)(Wroot + f * COUT);
#pragma unroll
        for (int c4 = 0; c4 < COUT / 4; ++c4) {
            float4 wr = w4r[c4], wo = w4o[c4];
            rel[c4 * 4 + 0] += af * wr.x;  root[c4 * 4 + 0] += hf * wo.x;
            rel[c4 * 4 + 1] += af * wr.y;  root[c4 * 4 + 1] += hf * wo.y;
            rel[c4 * 4 + 2] += af * wr.z;  root[c4 * 4 + 2] += hf * wo.z;
            rel[c4 * 4 + 3] += af * wr.w;  root[c4 * 4 + 3] += hf * wo.w;
        }
        __syncthreads();
    }

    const size_t ob = (size_t)NB * 3 * N_PTS + (size_t)b * COUT * N_PTS;
#pragma unroll
    for (int c = 0; c < COUT; ++c) {
        float acc = (rel[c] + brel[c]) + root[c];   // einsum + b_rel + einsum order
        out[ob + (size_t)c * N_PTS + i] = fmaxf(acc, 0.f);
    }
}

// ---------------- Fallback: proven round-7 monolithic kernel ----------------
__device__ __forceinline__ void insert3(float d, int c,
                                        float& v0, float& v1, float& v2,
                                        int& c0, int& c1, int& c2) {
    if (d < v2) {
        if (d < v1) {
            if (d < v0) { v2 = v1; c2 = c1; v1 = v0; c1 = c0; v0 = d; c0 = c; }
            else        { v2 = v1; c2 = c1; v1 = d;  c1 = c; }
        } else          { v2 = d;  c2 = c; }
    }
}

__global__ __launch_bounds__(64) void pcd_all(
    const float* __restrict__ xloc,
    const float* __restrict__ xfeat,
    const float* __restrict__ Wrel,
    const float* __restrict__ brel,
    const float* __restrict__ Wroot,
    float* __restrict__ out) {
    const int lane = threadIdx.x;
    const int row  = blockIdx.x;
    const int b    = row >> 12;
    const int i    = row & (N_PTS - 1);
    const float* xb = xloc + (size_t)b * 3 * N_PTS;

    if (lane < 3) {
        out[((size_t)b * 3 + lane) * N_PTS + i] = xb[(size_t)lane * N_PTS + i];
    }

    const float xi  = xb[i];
    const float yi  = xb[N_PTS + i];
    const float zi  = xb[2 * N_PTS + i];
    const float sqi = sq_exact(xi, yi, zi);

    float v0 = 1e30f, v1 = 1e30f, v2 = 1e30f;
    int   c0 = -1,    c1 = -1,    c2 = -1;

    for (int s = 0; s < 16; ++s) {
        int jb = s * 256 + lane * 4;
        float4 fx = *(const float4*)(xb + jb);
        float4 fy = *(const float4*)(xb + N_PTS + jb);
        float4 fz = *(const float4*)(xb + 2 * N_PTS + jb);
#pragma unroll
        for (int q = 0; q < 4; ++q) {
            float xj = (q == 0) ? fx.x : (q == 1) ? fx.y : (q == 2) ? fx.z : fx.w;
            float yj = (q == 0) ? fy.x : (q == 1) ? fy.y : (q == 2) ? fy.z : fy.w;
            float zj = (q == 0) ? fz.x : (q == 1) ? fz.y : (q == 2) ? fz.z : fz.w;
            int j = jb + q;
            float d = (j == i) ? 1e30f : dist_exact(xi, yi, zi, sqi, xj, yj, zj);
            insert3(d, s * 4 + q, v0, v1, v2, c0, c1, c2);
        }
    }

    u64 taken = 0;
    __shared__ int knn[KNN];

    for (int t = 0; t < KNN; ++t) {
        float bv = v0;
        int   bj = (c0 >= 0) ? (((c0 >> 2) << 8) + lane * 4 + (c0 & 3)) : (N_PTS - 1);
#pragma unroll
        for (int m = 1; m < 64; m <<= 1) {
            float ov = __shfl_xor(bv, m);
            int   oj = __shfl_xor(bj, m);
            if (ov < bv || (ov == bv && oj < bj)) { bv = ov; bj = oj; }
        }
        if (lane == 0) knn[t] = bj & (N_PTS - 1);
        int owner = (bj >> 2) & 63;
        if (lane == owner) {
            int cw = (((bj >> 8) << 2) | (bj & 3)) & 63;
            taken |= (1ull << cw);
            v0 = v1; c0 = c1; v1 = v2; c1 = c2; v2 = 1e30f; c2 = -1;
            if (v0 >= 1e30f) {
                v0 = v1 = v2 = 1e30f; c0 = c1 = c2 = -1;
                for (int s = 0; s < 16; ++s) {
                    int jb = s * 256 + lane * 4;
                    float4 fx = *(const float4*)(xb + jb);
                    float4 fy = *(const float4*)(xb + N_PTS + jb);
                    float4 fz = *(const float4*)(xb + 2 * N_PTS + jb);
#pragma unroll
                    for (int q = 0; q < 4; ++q) {
                        int cc = s * 4 + q;
                        if ((taken >> cc) & 1ull) continue;
                        int j = jb + q;
                        if (j == i) continue;
                        float xj = (q == 0) ? fx.x : (q == 1) ? fx.y : (q == 2) ? fx.z : fx.w;
                        float yj = (q == 0) ? fy.x : (q == 1) ? fy.y : (q == 2) ? fy.z : fy.w;
                        float zj = (q == 0) ? fz.x : (q == 1) ? fz.y : (q == 2) ? fz.z : fz.w;
                        float d = dist_exact(xi, yi, zi, sqi, xj, yj, zj);
                        insert3(d, cc, v0, v1, v2, c0, c1, c2);
                    }
                }
            }
        }
    }

    __syncthreads();

    __shared__ float aggf[FIN + 1];
    __shared__ float hif[FIN + 1];

    const float* xfb = xfeat + ((size_t)b * 64 + lane) * N_PTS;
    const float* xlb = xb + (size_t)(lane < 3 ? lane : 0) * N_PTS;
    float af = 0.f, al = 0.f;
    for (int t = 0; t < KNN; ++t) {
        int j = knn[t];
        af += xfb[j];
        if (lane < 3) al += xlb[j];
    }
    aggf[3 + lane] = af;
    hif[3 + lane]  = xfb[i];
    if (lane < 3) { aggf[lane] = al; hif[lane] = xlb[i]; }
    __syncthreads();

    float acc_rel = 0.f, acc_root = 0.f;
    for (int f = 0; f < FIN; ++f) {
        acc_rel  += aggf[f] * Wrel[f * COUT + lane];
        acc_root += hif[f]  * Wroot[f * COUT + lane];
    }
    float acc = (acc_rel + brel[lane]) + acc_root;
    acc = fmaxf(acc, 0.0f);
    out[(size_t)NB * 3 * N_PTS + ((((size_t)b << 6) | lane) << 12) + i] = acc;
}

extern "C" void kernel_launch(void* const* d_in, const int* in_sizes, int n_in,
                              void* d_out, int out_size, void* d_ws, size_t ws_size,
                              hipStream_t stream) {
    const float* xloc  = nullptr;
    const float* xfeat = nullptr;
    const float* Wrel  = nullptr;
    const float* brel  = nullptr;
    const float* Wroot = nullptr;
    for (int idx = 0; idx < n_in; ++idx) {
        const long long s = in_sizes[idx];
        const float* p = (const float*)d_in[idx];
        if (s == 98304LL || s == 393216LL)          { xloc = p; }
        else if (s == 2097152LL || s == 8388608LL)  { xfeat = p; }
        else if (s == 4288LL || s == 17152LL)       { if (!Wrel) Wrel = p; else Wroot = p; }
        else if (s == 64LL || s == 256LL)           { brel = p; }
    }
    if (!xloc || !xfeat || !Wrel || !brel || !Wroot) {
        xloc  = (const float*)d_in[0];
        xfeat = (const float*)d_in[1];
        Wrel  = (const float*)d_in[2];
        brel  = (const float*)d_in[3];
        Wroot = (const float*)d_in[4];
    }

    const size_t KNN_BYTES = (size_t)NB * N_PTS * KNN * sizeof(u16);  // 1.31 MB
    if (d_ws != nullptr && ws_size >= KNN_BYTES) {
        u16* knn_ws = (u16*)d_ws;
        knn_pt_kernel<<<dim3(NB * N_PTS / 64), dim3(64), 0, stream>>>(xloc, knn_ws);
        conv_tile_kernel<<<dim3(NB * 32), dim3(128), 0, stream>>>(
            xloc, xfeat, Wrel, brel, Wroot, knn_ws, (float*)d_out);
    } else {
        pcd_all<<<dim3(NB * N_PTS), dim3(64), 0, stream>>>(
            xloc, xfeat, Wrel, brel, Wroot, (float*)d_out);
    }
}

// Round 12
// 456.151 us; speedup vs baseline: 2.4012x; 1.9871x over previous
//
#include <hip/hip_runtime.h>

#define N_PTS 4096
#define NB    8
#define KNN   20
#define FIN   67
#define COUT  64
#define SEG   4
#define SEGN  (N_PTS / SEG)   // 1024 candidates per segment-thread
#define SLOTS 24              // LDS stack slots per thread

typedef unsigned short u16;
typedef unsigned int   u32;
typedef unsigned long long u64;

__device__ __forceinline__ float finf() { return __uint_as_float(0x7f800000u); }

// sq = (x*x + y*y) + z*z, all f32, no FMA (matches np op order).
__device__ __forceinline__ float sq_exact(float x, float y, float z) {
#pragma clang fp contract(off)
    float s = (x * x + y * y) + z * z;
    return s;
}

// dist = (sq_i - 2*dot) + sq_j, dot = (x_i*x_j + y_i*y_j) + z_i*z_j, no FMA.
__device__ __forceinline__ float dist_from_sq(float xi, float yi, float zi, float sqi,
                                              float xj, float yj, float zj, float sqj) {
#pragma clang fp contract(off)
    float d0 = xi * xj, d1 = yi * yj, d2 = zi * zj;
    float dot = (d0 + d1) + d2;
    float d = (sqi - 2.0f * dot) + sqj;
    return d;
}

__device__ __forceinline__ float dist_exact(float xi, float yi, float zi, float sqi,
                                            float xj, float yj, float zj) {
#pragma clang fp contract(off)
    float d0 = xi * xj, d1 = yi * yj, d2 = zi * zj;
    float dot = (d0 + d1) + d2;
    float sqj = (xj * xj + yj * yj) + zj * zj;
    float d = (sqi - 2.0f * dot) + sqj;
    return d;
}

// Compare-exchange on (d, j) lexicographic (strict) — matches lax.top_k order.
// Puts the smaller element in (ad, aj).
__device__ __forceinline__ void cswap(float& ad, u32& aj, float& bd, u32& bj) {
    bool sw = (bd < ad) || ((bd == ad) && (bj < aj));
    float nad = sw ? bd : ad, nbd = sw ? ad : bd;
    u32   naj = sw ? bj : aj, nbj = sw ? aj : bj;
    ad = nad; bd = nbd; aj = naj; bj = nbj;
}

// Merge the LDS append-stack (cnt valid entries of SLOTS) into the sorted
// 32-entry list (ld, lj) keeping the exact 32 smallest. All register indices
// are compile-time (bit-op bitonic loops, fully unrolled).
__device__ __forceinline__ void merge_stack(float (&ld)[32], u32 (&lj)[32],
                                            const uint2* mystk, int cnt) {
    float bd[32]; u32 bj[32];
#pragma unroll
    for (int t = 0; t < SLOTS; ++t) {
        uint2 v = mystk[t];
        bool valid = t < cnt;
        bd[t] = valid ? __uint_as_float(v.x) : finf();
        bj[t] = valid ? v.y : 0xFFFFFFFFu;
    }
#pragma unroll
    for (int t = SLOTS; t < 32; ++t) { bd[t] = finf(); bj[t] = 0xFFFFFFFFu; }

    // Bitonic sort 32 ascending (240 comparators, bit-ops only).
#pragma unroll
    for (int k = 2; k <= 32; k <<= 1) {
#pragma unroll
        for (int s = k >> 1; s > 0; s >>= 1) {
#pragma unroll
            for (int t = 0; t < 32; ++t) {
                int l = t ^ s;
                if (l > t) {
                    if ((t & k) == 0) cswap(bd[t], bj[t], bd[l], bj[l]);
                    else              cswap(bd[l], bj[l], bd[t], bj[t]);
                }
            }
        }
    }

    // Keep-lower-half merge: ld asc + bd asc -> elementwise min(ld[t], bd[31-t])
    // = exact smallest 32 of the union, bitonic. Then bitonic-merge to asc.
#pragma unroll
    for (int t = 0; t < 32; ++t) cswap(ld[t], lj[t], bd[31 - t], bj[31 - t]);
#pragma unroll
    for (int k = 16; k >= 1; k >>= 1) {
#pragma unroll
        for (int t = 0; t < 32; ++t) {
            if ((t & k) == 0) cswap(ld[t], lj[t], ld[t | k], lj[t | k]);
        }
    }
}

// ---------------- Kernel 1: kNN, (query, segment) per thread ----------------
// Block = 256 threads = 64 queries x 4 segments of 1024 candidates.
// Per thread: exact top-20 of its segment via threshold gate (d < 20th entry,
// exact by the ascending-j tie argument) + LDS append stack + static bitonic
// merges. Then a 4-way pointer merge per query produces the global top-20.
__global__ __launch_bounds__(256) void knn_seg_kernel(
    const float* __restrict__ xloc, u16* __restrict__ knn_out) {
    __shared__ uint2 stack[256 * SLOTS];      // 48 KB
    const int tid  = threadIdx.x;
    const int lane = tid & 63;                // query within tile
    const int seg  = tid >> 6;                // candidate segment (wave-uniform)
    const int blk  = blockIdx.x;              // b*64 + qtile
    const int b    = blk >> 6;
    const int i    = ((blk & 63) << 6) | lane;
    const float* xb = xloc + (size_t)b * 3 * N_PTS;

    const float xi = xb[i], yi = xb[N_PTS + i], zi = xb[2 * N_PTS + i];
    const float sqi = sq_exact(xi, yi, zi);

    float ld[32]; u32 lj[32];
#pragma unroll
    for (int t = 0; t < 32; ++t) { ld[t] = finf(); lj[t] = 0xFFFFFFFFu; }
    float thr = finf();
    int cnt = 0;
    uint2* mystk = &stack[tid * SLOTS];

    const int cbase = seg * SEGN;
    for (int c = 0; c < SEGN; c += 4) {
        const int cc = cbase + c;
        float4 fx = *(const float4*)(xb + cc);
        float4 fy = *(const float4*)(xb + N_PTS + cc);
        float4 fz = *(const float4*)(xb + 2 * N_PTS + cc);
#pragma unroll
        for (int q = 0; q < 4; ++q) {
            float xj = (q == 0) ? fx.x : (q == 1) ? fx.y : (q == 2) ? fx.z : fx.w;
            float yj = (q == 0) ? fy.x : (q == 1) ? fy.y : (q == 2) ? fy.z : fy.w;
            float zj = (q == 0) ? fz.x : (q == 1) ? fz.y : (q == 2) ? fz.z : fz.w;
            float sqj = sq_exact(xj, yj, zj);
            float d = dist_from_sq(xi, yi, zi, sqi, xj, yj, zj, sqj);
            int j = cc + q;
            // Gate d < thr (= current 20th entry) is EXACT: a rejected d == thr
            // candidate has larger j (ascending scan) => lex-rank > 20 forever.
            bool ok = (j != i) && (d < thr);
            if (ok) {
                mystk[cnt] = make_uint2(__float_as_uint(d), (u32)j);
                ++cnt;
            }
        }
        // Entering a chunk every lane has cnt <= 20; +4 inserts max => <= 24. ✓
        if (__any(cnt >= SLOTS - 3)) {
            merge_stack(ld, lj, mystk, cnt);
            thr = ld[KNN - 1];
            cnt = 0;
        }
    }
    merge_stack(ld, lj, mystk, cnt);          // drain

    // Publish this segment's exact top-20 (sorted by (d,j)) to LDS.
#pragma unroll
    for (int t = 0; t < KNN; ++t)
        mystk[t] = make_uint2(__float_as_uint(ld[t]), lj[t]);
    __syncthreads();

    // Final 4-way merge per query (threads 0..63, one query each).
    if (tid < 64) {
        const int q = tid;
        const int row = (b << 12) | ((blk & 63) << 6) | q;
        int p0 = 0, p1 = 0, p2 = 0, p3 = 0;
        uint2 v0 = stack[(q      ) * SLOTS];
        uint2 v1 = stack[(q +  64) * SLOTS];
        uint2 v2 = stack[(q + 128) * SLOTS];
        uint2 v3 = stack[(q + 192) * SLOTS];
        float d0 = __uint_as_float(v0.x), d1 = __uint_as_float(v1.x);
        float d2 = __uint_as_float(v2.x), d3 = __uint_as_float(v3.x);
        u32 j0 = v0.y, j1 = v1.y, j2 = v2.y, j3 = v3.y;
#pragma unroll
        for (int t = 0; t < KNN; ++t) {
            bool a = (d0 < d1) || ((d0 == d1) && (j0 < j1));
            float dA = a ? d0 : d1;  u32 jA = a ? j0 : j1;  int sA = a ? 0 : 1;
            bool bo = (d2 < d3) || ((d2 == d3) && (j2 < j3));
            float dB = bo ? d2 : d3; u32 jB = bo ? j2 : j3; int sB = bo ? 2 : 3;
            bool f = (dA < dB) || ((dA == dB) && (jA < jB));
            u32 jm = f ? jA : jB;    int sm = f ? sA : sB;
            knn_out[(size_t)row * KNN + t] = (u16)jm;
            if (sm == 0) {
                ++p0; uint2 v = stack[q * SLOTS + p0];
                bool okp = p0 < KNN;
                d0 = okp ? __uint_as_float(v.x) : finf(); j0 = okp ? v.y : 0xFFFFFFFFu;
            } else if (sm == 1) {
                ++p1; uint2 v = stack[(q + 64) * SLOTS + p1];
                bool okp = p1 < KNN;
                d1 = okp ? __uint_as_float(v.x) : finf(); j1 = okp ? v.y : 0xFFFFFFFFu;
            } else if (sm == 2) {
                ++p2; uint2 v = stack[(q + 128) * SLOTS + p2];
                bool okp = p2 < KNN;
                d2 = okp ? __uint_as_float(v.x) : finf(); j2 = okp ? v.y : 0xFFFFFFFFu;
            } else {
                ++p3; uint2 v = stack[(q + 192) * SLOTS + p3];
                bool okp = p3 < KNN;
                d3 = okp ? __uint_as_float(v.x) : finf(); j3 = okp ? v.y : 0xFFFFFFFFu;
            }
        }
    }
}

// ---------------- Kernel 2: conv, coalesced tile (proven, ~165us) ----------------
__global__ __launch_bounds__(128) void conv_tile_kernel(
    const float* __restrict__ xloc,
    const float* __restrict__ xfeat,
    const float* __restrict__ Wrel,
    const float* __restrict__ brel,
    const float* __restrict__ Wroot,
    const u16* __restrict__ knn_in,
    float* __restrict__ out) {
    __shared__ float rowbuf[2][N_PTS];        // 32 KB
    const int tid = threadIdx.x;
    const int blk = blockIdx.x;               // b*32 + tile
    const int b   = blk >> 5;
    const int i   = ((blk & 31) << 7) | tid;  // point index within batch
    const float* xb = xloc + (size_t)b * 3 * N_PTS;
    const float* fb = xfeat + (size_t)b * 64 * N_PTS;

    // Output 0 passthrough (bit-exact, coalesced).
#pragma unroll
    for (int c = 0; c < 3; ++c)
        out[((size_t)b * 3 + c) * N_PTS + i] = xb[(size_t)c * N_PTS + i];

    // This thread's neighbor list -> registers (static indexing only).
    u32 kl[KNN / 2];
    const u32* kp = (const u32*)(knn_in + (size_t)((b << 12) | i) * KNN);
#pragma unroll
    for (int w = 0; w < KNN / 2; ++w) kl[w] = kp[w];
    int jj[KNN];
#pragma unroll
    for (int t = 0; t < KNN; ++t) jj[t] = (int)((kl[t >> 1] >> ((t & 1) * 16)) & 0xFFFFu);

    float rel[COUT], root[COUT];
#pragma unroll
    for (int c = 0; c < COUT; ++c) { rel[c] = 0.f; root[c] = 0.f; }

    auto stage = [&](int f) {
        const float* src = (f < 3) ? (xb + (size_t)f * N_PTS)
                                   : (fb + (size_t)(f - 3) * N_PTS);
        const float4* s4 = (const float4*)src;
        float4* d4 = (float4*)rowbuf[f & 1];
#pragma unroll
        for (int w = 0; w < 8; ++w) {
            int idx = w * 128 + tid;
            d4[idx] = s4[idx];
        }
    };

    stage(0);
    __syncthreads();

    for (int f = 0; f < FIN; ++f) {
        if (f + 1 < FIN) stage(f + 1);
        const float* cur = rowbuf[f & 1];
        float hf = cur[i];
        float af = 0.f;
#pragma unroll
        for (int t = 0; t < KNN; ++t) af += cur[jj[t]];   // ascending (dist,idx) order

        const float4* w4r = (const float4*)(Wrel + f * COUT);
        const float4* w4o = (const float4*)(Wroot + f * COUT);
#pragma unroll
        for (int c4 = 0; c4 < COUT / 4; ++c4) {
            float4 wr = w4r[c4], wo = w4o[c4];
            rel[c4 * 4 + 0] += af * wr.x;  root[c4 * 4 + 0] += hf * wo.x;
            rel[c4 * 4 + 1] += af * wr.y;  root[c4 * 4 + 1] += hf * wo.y;
            rel[c4 * 4 + 2] += af * wr.z;  root[c4 * 4 + 2] += hf * wo.z;
            rel[c4 * 4 + 3] += af * wr.w;  root[c4 * 4 + 3] += hf * wo.w;
        }
        __syncthreads();
    }

    const size_t ob = (size_t)NB * 3 * N_PTS + (size_t)b * COUT * N_PTS;
#pragma unroll
    for (int c = 0; c < COUT; ++c) {
        float acc = (rel[c] + brel[c]) + root[c];   // einsum + b_rel + einsum order
        out[ob + (size_t)c * N_PTS + i] = fmaxf(acc, 0.f);
    }
}

// ---------------- Fallback: proven round-7 monolithic kernel ----------------
__device__ __forceinline__ void insert3(float d, int c,
                                        float& v0, float& v1, float& v2,
                                        int& c0, int& c1, int& c2) {
    if (d < v2) {
        if (d < v1) {
            if (d < v0) { v2 = v1; c2 = c1; v1 = v0; c1 = c0; v0 = d; c0 = c; }
            else        { v2 = v1; c2 = c1; v1 = d;  c1 = c; }
        } else          { v2 = d;  c2 = c; }
    }
}

__global__ __launch_bounds__(64) void pcd_all(
    const float* __restrict__ xloc,
    const float* __restrict__ xfeat,
    const float* __restrict__ Wrel,
    const float* __restrict__ brel,
    const float* __restrict__ Wroot,
    float* __restrict__ out) {
    const int lane = threadIdx.x;
    const int row  = blockIdx.x;
    const int b    = row >> 12;
    const int i    = row & (N_PTS - 1);
    const float* xb = xloc + (size_t)b * 3 * N_PTS;

    if (lane < 3) {
        out[((size_t)b * 3 + lane) * N_PTS + i] = xb[(size_t)lane * N_PTS + i];
    }

    const float xi  = xb[i];
    const float yi  = xb[N_PTS + i];
    const float zi  = xb[2 * N_PTS + i];
    const float sqi = sq_exact(xi, yi, zi);

    float v0 = 1e30f, v1 = 1e30f, v2 = 1e30f;
    int   c0 = -1,    c1 = -1,    c2 = -1;

    for (int s = 0; s < 16; ++s) {
        int jb = s * 256 + lane * 4;
        float4 fx = *(const float4*)(xb + jb);
        float4 fy = *(const float4*)(xb + N_PTS + jb);
        float4 fz = *(const float4*)(xb + 2 * N_PTS + jb);
#pragma unroll
        for (int q = 0; q < 4; ++q) {
            float xj = (q == 0) ? fx.x : (q == 1) ? fx.y : (q == 2) ? fx.z : fx.w;
            float yj = (q == 0) ? fy.x : (q == 1) ? fy.y : (q == 2) ? fy.z : fy.w;
            float zj = (q == 0) ? fz.x : (q == 1) ? fz.y : (q == 2) ? fz.z : fz.w;
            int j = jb + q;
            float d = (j == i) ? 1e30f : dist_exact(xi, yi, zi, sqi, xj, yj, zj);
            insert3(d, s * 4 + q, v0, v1, v2, c0, c1, c2);
        }
    }

    u64 taken = 0;
    __shared__ int knn[KNN];

    for (int t = 0; t < KNN; ++t) {
        float bv = v0;
        int   bj = (c0 >= 0) ? (((c0 >> 2) << 8) + lane * 4 + (c0 & 3)) : (N_PTS - 1);
#pragma unroll
        for (int m = 1; m < 64; m <<= 1) {
            float ov = __shfl_xor(bv, m);
            int   oj = __shfl_xor(bj, m);
            if (ov < bv || (ov == bv && oj < bj)) { bv = ov; bj = oj; }
        }
        if (lane == 0) knn[t] = bj & (N_PTS - 1);
        int owner = (bj >> 2) & 63;
        if (lane == owner) {
            int cw = (((bj >> 8) << 2) | (bj & 3)) & 63;
            taken |= (1ull << cw);
            v0 = v1; c0 = c1; v1 = v2; c1 = c2; v2 = 1e30f; c2 = -1;
            if (v0 >= 1e30f) {
                v0 = v1 = v2 = 1e30f; c0 = c1 = c2 = -1;
                for (int s = 0; s < 16; ++s) {
                    int jb = s * 256 + lane * 4;
                    float4 fx = *(const float4*)(xb + jb);
                    float4 fy = *(const float4*)(xb + N_PTS + jb);
                    float4 fz = *(const float4*)(xb + 2 * N_PTS + jb);
#pragma unroll
                    for (int q = 0; q < 4; ++q) {
                        int cc = s * 4 + q;
                        if ((taken >> cc) & 1ull) continue;
                        int j = jb + q;
                        if (j == i) continue;
                        float xj = (q == 0) ? fx.x : (q == 1) ? fx.y : (q == 2) ? fx.z : fx.w;
                        float yj = (q == 0) ? fy.x : (q == 1) ? fy.y : (q == 2) ? fy.z : fy.w;
                        float zj = (q == 0) ? fz.x : (q == 1) ? fz.y : (q == 2) ? fz.z : fz.w;
                        float d = dist_exact(xi, yi, zi, sqi, xj, yj, zj);
                        insert3(d, cc, v0, v1, v2, c0, c1, c2);
                    }
                }
            }
        }
    }

    __syncthreads();

    __shared__ float aggf[FIN + 1];
    __shared__ float hif[FIN + 1];

    const float* xfb = xfeat + ((size_t)b * 64 + lane) * N_PTS;
    const float* xlb = xb + (size_t)(lane < 3 ? lane : 0) * N_PTS;
    float af = 0.f, al = 0.f;
    for (int t = 0; t < KNN; ++t) {
        int j = knn[t];
        af += xfb[j];
        if (lane < 3) al += xlb[j];
    }
    aggf[3 + lane] = af;
    hif[3 + lane]  = xfb[i];
    if (lane < 3) { aggf[lane] = al; hif[lane] = xlb[i]; }
    __syncthreads();

    float acc_rel = 0.f, acc_root = 0.f;
    for (int f = 0; f < FIN; ++f) {
        acc_rel  += aggf[f] * Wrel[f * COUT + lane];
        acc_root += hif[f]  * Wroot[f * COUT + lane];
    }
    float acc = (acc_rel + brel[lane]) + acc_root;
    acc = fmaxf(acc, 0.0f);
    out[(size_t)NB * 3 * N_PTS + ((((size_t)b << 6) | lane) << 12) + i] = acc;
}

extern "C" void kernel_launch(void* const* d_in, const int* in_sizes, int n_in,
                              void* d_out, int out_size, void* d_ws, size_t ws_size,
                              hipStream_t stream) {
    const float* xloc  = nullptr;
    const float* xfeat = nullptr;
    const float* Wrel  = nullptr;
    const float* brel  = nullptr;
    const float* Wroot = nullptr;
    for (int idx = 0; idx < n_in; ++idx) {
        const long long s = in_sizes[idx];
        const float* p = (const float*)d_in[idx];
        if (s == 98304LL || s == 393216LL)          { xloc = p; }
        else if (s == 2097152LL || s == 8388608LL)  { xfeat = p; }
        else if (s == 4288LL || s == 17152LL)       { if (!Wrel) Wrel = p; else Wroot = p; }
        else if (s == 64LL || s == 256LL)           { brel = p; }
    }
    if (!xloc || !xfeat || !Wrel || !brel || !Wroot) {
        xloc  = (const float*)d_in[0];
        xfeat = (const float*)d_in[1];
        Wrel  = (const float*)d_in[2];
        brel  = (const float*)d_in[3];
        Wroot = (const float*)d_in[4];
    }

    const size_t KNN_BYTES = (size_t)NB * N_PTS * KNN * sizeof(u16);  // 1.31 MB
    if (d_ws != nullptr && ws_size >= KNN_BYTES) {
        u16* knn_ws = (u16*)d_ws;
        knn_seg_kernel<<<dim3(NB * 64), dim3(256), 0, stream>>>(xloc, knn_ws);
        conv_tile_kernel<<<dim3(NB * 32), dim3(128), 0, stream>>>(
            xloc, xfeat, Wrel, brel, Wroot, knn_ws, (float*)d_out);
    } else {
        pcd_all<<<dim3(NB * N_PTS), dim3(64), 0, stream>>>(
            xloc, xfeat, Wrel, brel, Wroot, (float*)d_out);
    }
}